// Round 9
// baseline (443.373 us; speedup 1.0000x reference)
//
#include <hip/hip_runtime.h>
#include <hip/hip_cooperative_groups.h>
#include <hip/hip_bf16.h>
#include <math.h>

namespace cg = cooperative_groups;

typedef _Float16 f16;
typedef _Float16 f16x8 __attribute__((ext_vector_type(8)));
typedef _Float16 f16x4 __attribute__((ext_vector_type(4)));
typedef float f32x4 __attribute__((ext_vector_type(4)));

#define MFMA(a, b, c) __builtin_amdgcn_mfma_f32_16x16x32_f16((a), (b), (c), 0, 0, 0)

constexpr int Dd = 64;
constexpr int Hh = 128;
constexpr int Nn = 4096;
constexpr int NT = 32;
constexpr int NVB = (Nn / NT) * Dd;  // 8192 virtual blocks
constexpr float SLP = 0.2f;
constexpr float INV2K = 1.0f / 2048.0f;

// Per-d f16 layout in d_ws:
//   [0,16384)     W1: h0 (hi 4096|lo 4096 swzK64), h1
//   [16384,49152) W2: h0 (hi 8192|lo 8192 swz), h1
//   [49152,81920) W3: h0, h1
constexpr int PD = 81920;
constexpr size_t W1L_OFF = (size_t)Dd * PD * 2;  // bytes; then w1last f32[64][128]
constexpr size_t WS_NEEDED = W1L_OFF + (size_t)Dd * Hh * 4;

__device__ __forceinline__ int swz(int r, int c) {
  return (r << 7) + ((((c >> 3) ^ (r & 15)) << 3) | (c & 7));
}
__device__ __forceinline__ int swzK64(int r, int c) {
  return (r << 6) + (((((c >> 3) ^ r) & 7) << 3) | (c & 7));
}
__device__ __forceinline__ int swzF(int n, int h) {
  return (n << 7) + ((((h >> 2) ^ n) & 31) << 2) + (h & 3);
}

struct HL { f16 h, l; };
__device__ __forceinline__ HL split(float v) {
  HL r;
  r.h = (f16)v;
  r.l = (f16)((v - (float)r.h) * 2048.0f);
  return r;
}

// Async contiguous global->LDS, 512 threads: nbytes multiple of 8192
__device__ __forceinline__ void cp_lds_async512(const void* g, void* l, int nbytes, int tid) {
  const int lane = tid & 63, wv = tid >> 6;
  for (int base = wv * 1024; base < nbytes; base += 8192) {
    __builtin_amdgcn_global_load_lds(
        (const __attribute__((address_space(1))) void*)((const char*)g + base + lane * 16),
        (__attribute__((address_space(3))) void*)((char*)l + base), 16, 0, 0);
  }
}

// One W-half of a mid layer, one h-tile per wave. All operands from LDS.
__device__ __forceinline__ void mid_half(
    const f16* AH, const f16* AL, const f16* DH, const f16* DL,
    const f16* WH, const f16* WL, int ra, int hr, int quad,
    f32x4& aP, f32x4& aS, f32x4& dP, f32x4& dS) {
#pragma unroll
  for (int kc = 0; kc < 4; kc++) {
    int ko = kc * 32 + quad * 8;
    f16x8 xh = *(const f16x8*)&AH[swz(ra, ko)];
    f16x8 xl = *(const f16x8*)&AL[swz(ra, ko)];
    f16x8 yh = *(const f16x8*)&DH[swz(ra, ko)];
    f16x8 yl = *(const f16x8*)&DL[swz(ra, ko)];
    f16x8 wh = *(const f16x8*)&WH[swz(hr, ko)];
    f16x8 wl = *(const f16x8*)&WL[swz(hr, ko)];
    aP = MFMA(wh, xh, aP);
    aS = MFMA(wl, xh, aS);
    aS = MFMA(wh, xl, aS);
    dP = MFMA(wh, yh, dP);
    dS = MFMA(wl, yh, dS);
    dS = MFMA(wh, yl, dS);
  }
}

// ---------------- fused cooperative persistent kernel ------------------------
// Phase A: weight split/swizzle into d_ws (grid-stride, coalesced writes).
// grid.sync. Phase B: grid-stride over 8192 virtual tiles (R6 body).
// Grid is sized by the runtime occupancy query in kernel_launch.
__global__ __launch_bounds__(512, 4)
void np_prior_coop(const float* __restrict__ x,
                   const float* __restrict__ W1, const float* __restrict__ W2,
                   const float* __restrict__ W3,
                   const float* __restrict__ b1, const float* __restrict__ b2,
                   const float* __restrict__ b3, const float* __restrict__ W4,
                   const float* __restrict__ b4, f16* __restrict__ wsf,
                   float* __restrict__ w1lg,
                   float* __restrict__ out_res, float* __restrict__ out_log) {
  __shared__ float4 smem[4096];  // 64 KB
  f16* AH = (f16*)smem;
  f16* AL = AH + NT * 128;
  f16* DH = AL + NT * 128;
  f16* DL = DH + NT * 128;
  f16* Wreg = (f16*)((char*)smem + 32768);
  float* A3F = (float*)smem;
  float* D3F = (float*)((char*)smem + 16384);

  const int tid = threadIdx.x;
  const int gtid = blockIdx.x * 512 + tid;
  const int gsz = gridDim.x * 512;

  // ======== Phase A: weight preprocessing (10240 f16x8 chunks per d) ========
  for (int g = gtid; g < Dd * 10240; g += gsz) {
    int d = g / 10240;
    int r = g - d * 10240;
    f16* outd = wsf + (size_t)d * PD;
    float vv[8];
    f16* dst;
    if (r < 2048) {
      int rem = r & 1023;
      int hf = r >> 10, plane = rem >> 9, j = rem & 511;
      int row = j >> 3, sc = j & 7;
      int h = hf * 64 + row;
      int k0 = (sc ^ (row & 7)) << 3;
      const float* src = W1 + d * 8320 + h * 65 + k0;
#pragma unroll
      for (int e = 0; e < 8; e++) vv[e] = src[e];
      dst = outd + r * 8;
      if (plane) {
#pragma unroll
        for (int e = 0; e < 8; e++) {
          f16 hi = (f16)vv[e];
          vv[e] = (vv[e] - (float)hi) * 2048.0f;
        }
      }
    } else {
      int r2 = r - 2048;
      int wsec = r2 >> 11;  // 0=W2h0 1=W2h1 2=W3h0 3=W3h1
      int rr = r2 & 2047;
      int plane = rr >> 10, j = rr & 1023;
      int row = j >> 4, sc = j & 15;
      int k0 = (sc ^ (row & 15)) << 3;
      const float* base = (wsec < 2 ? W2 : W3) + d * 16384 + (wsec & 1) * 8192;
      const float* src = base + row * 128 + k0;
      float4 v0 = *(const float4*)src, v1 = *(const float4*)(src + 4);
      vv[0] = v0.x; vv[1] = v0.y; vv[2] = v0.z; vv[3] = v0.w;
      vv[4] = v1.x; vv[5] = v1.y; vv[6] = v1.z; vv[7] = v1.w;
      dst = outd + 16384 + (wsec >> 1) * 32768 + (wsec & 1) * 16384 + rr * 8;
      if (plane) {
#pragma unroll
        for (int e = 0; e < 8; e++) {
          f16 hi = (f16)vv[e];
          vv[e] = (vv[e] - (float)hi) * 2048.0f;
        }
      }
    }
    f16x8 o;
#pragma unroll
    for (int e = 0; e < 8; e++) o[e] = (f16)vv[e];
    *(f16x8*)dst = o;
  }
  for (int g = gtid; g < Dd * Hh; g += gsz)
    w1lg[g] = W1[(g >> 7) * 8320 + (g & 127) * 65 + 64];
  for (int g = gtid; g < Nn; g += gsz) out_log[g] = 0.f;

  __threadfence();
  cg::this_grid().sync();
  __threadfence();

  // ======== Phase B: grid-stride over 8192 virtual tiles ====================
  const int lane = tid & 63, wv = tid >> 6, l15 = lane & 15, quad = lane >> 4;
  const int nt = wv & 1, wq = wv >> 1;
  const int ra = nt * 16 + l15;
  const int hr = wq * 16 + l15;
  const f32x4 zero = {0.f, 0.f, 0.f, 0.f};

  for (int v = blockIdx.x; v < NVB; v += gridDim.x) {
    const int d = v & 63, n0 = (v >> 6) * NT;
    const f16* wd = wsf + (size_t)d * PD;
    const float* w1l = w1lg + d * Hh;
    const float* b1d = b1 + d * Hh;

    __syncthreads();  // protect smem overlay reuse across iterations
    cp_lds_async512(wd, Wreg, 16384, tid);  // W1-h0
    {
      int n = tid >> 4, k4 = (tid & 15) << 2;
      int ng = n0 + n, bb = ng >> 8, tt = ng & 255;
      float4 vx = *(const float4*)&x[(bb * 257 + tt) * 64 + k4];
      HL a = split(vx.x), b = split(vx.y), c = split(vx.z), e = split(vx.w);
      int o = swz(n, k4);
      *(f16x4*)&AH[o] = f16x4{a.h, b.h, c.h, e.h};
      *(f16x4*)&AL[o] = f16x4{a.l, b.l, c.l, e.l};
    }
    float xtv;
    {
      int ng = n0 + ra, bb = ng >> 8, tt = ng & 255;
      xtv = x[(bb * 257 + tt + 1) * 64 + d];
    }
    __syncthreads();

    // ---- Layer 1 (K=64)
    f32x4 l1P[2], l1S[2];
#pragma unroll
    for (int hf = 0; hf < 2; hf++) {
      if (hf == 1) {
        __syncthreads();
        cp_lds_async512(wd + 8192, Wreg, 16384, tid);
        __syncthreads();
      }
      l1P[hf] = zero; l1S[hf] = zero;
#pragma unroll
      for (int kc = 0; kc < 2; kc++) {
        int ko = kc * 32 + quad * 8;
        f16x8 xh = *(const f16x8*)&AH[swz(ra, ko)];
        f16x8 xl = *(const f16x8*)&AL[swz(ra, ko)];
        f16x8 wh = *(const f16x8*)&Wreg[swzK64(hr, ko)];
        f16x8 wl = *(const f16x8*)&Wreg[4096 + swzK64(hr, ko)];
        l1P[hf] = MFMA(wh, xh, l1P[hf]);
        l1S[hf] = MFMA(wl, xh, l1S[hf]);
        l1S[hf] = MFMA(wh, xl, l1S[hf]);
      }
    }
    __syncthreads();
    cp_lds_async512(wd + 16384, Wreg, 32768, tid);  // W2-h0

    // ---- L1 epilogue
#pragma unroll
    for (int hf = 0; hf < 2; hf++) {
      int hb = hf * 64 + wq * 16 + quad * 4;
      float4 wv4 = *(const float4*)&w1l[hb];
      float4 bv4 = *(const float4*)&b1d[hb];
      f16x4 ah, al, dh, dl;
#pragma unroll
      for (int j = 0; j < 4; j++) {
        float w1j = (&wv4.x)[j];
        float p = l1P[hf][j] + l1S[hf][j] * INV2K + xtv * w1j + (&bv4.x)[j];
        float s = p > 0.f ? 1.f : SLP;
        HL av = split(p * s), dv = split(s * w1j);
        ah[j] = av.h; al[j] = av.l; dh[j] = dv.h; dl[j] = dv.l;
      }
      int o = swz(ra, hb);
      *(f16x4*)&AH[o] = ah; *(f16x4*)&AL[o] = al;
      *(f16x4*)&DH[o] = dh; *(f16x4*)&DL[o] = dl;
    }
    __syncthreads();

    // ---- Layer 2
    f32x4 aP[2], aS[2], dP[2], dS[2];
#pragma unroll
    for (int hf = 0; hf < 2; hf++) {
      if (hf == 1) {
        __syncthreads();
        cp_lds_async512(wd + 32768, Wreg, 32768, tid);  // W2-h1
        __syncthreads();
      }
      aP[hf] = zero; aS[hf] = zero; dP[hf] = zero; dS[hf] = zero;
      mid_half(AH, AL, DH, DL, Wreg, Wreg + 8192, ra, hr, quad,
               aP[hf], aS[hf], dP[hf], dS[hf]);
    }
    __syncthreads();
    cp_lds_async512(wd + 49152, Wreg, 32768, tid);  // W3-h0

    // ---- L2 epilogue
    {
      const float* b2d = b2 + d * Hh;
#pragma unroll
      for (int hf = 0; hf < 2; hf++) {
        int hb = hf * 64 + wq * 16 + quad * 4;
        float4 bv4 = *(const float4*)&b2d[hb];
        f16x4 ah, al, dh, dl;
#pragma unroll
        for (int j = 0; j < 4; j++) {
          float p = aP[hf][j] + aS[hf][j] * INV2K + (&bv4.x)[j];
          float s = p > 0.f ? 1.f : SLP;
          float dd = s * (dP[hf][j] + dS[hf][j] * INV2K);
          HL av = split(p * s), dv = split(dd);
          ah[j] = av.h; al[j] = av.l; dh[j] = dv.h; dl[j] = dv.l;
        }
        int o = swz(ra, hb);
        *(f16x4*)&AH[o] = ah; *(f16x4*)&AL[o] = al;
        *(f16x4*)&DH[o] = dh; *(f16x4*)&DL[o] = dl;
      }
    }
    __syncthreads();

    // ---- Layer 3
#pragma unroll
    for (int hf = 0; hf < 2; hf++) {
      if (hf == 1) {
        __syncthreads();
        cp_lds_async512(wd + 65536, Wreg, 32768, tid);  // W3-h1
        __syncthreads();
      }
      aP[hf] = zero; aS[hf] = zero; dP[hf] = zero; dS[hf] = zero;
      mid_half(AH, AL, DH, DL, Wreg, Wreg + 8192, ra, hr, quad,
               aP[hf], aS[hf], dP[hf], dS[hf]);
    }
    __syncthreads();

    // ---- L3 epilogue -> swizzled f32 overlay
    {
      const float* b3d = b3 + d * Hh;
#pragma unroll
      for (int hf = 0; hf < 2; hf++) {
        int hb = hf * 64 + wq * 16 + quad * 4;
        float4 bv4 = *(const float4*)&b3d[hb];
        float4 pa, pd;
#pragma unroll
        for (int j = 0; j < 4; j++) {
          float p = aP[hf][j] + aS[hf][j] * INV2K + (&bv4.x)[j];
          float s = p > 0.f ? 1.f : SLP;
          (&pa.x)[j] = p * s;
          (&pd.x)[j] = s * (dP[hf][j] + dS[hf][j] * INV2K);
        }
        *(float4*)&A3F[swzF(ra, hb)] = pa;
        *(float4*)&D3F[swzF(ra, hb)] = pd;
      }
    }
    __syncthreads();

    // ---- Layer 4
    {
      int n = tid >> 4, g16 = tid & 15;
      const float* w4d = W4 + d * Hh;
      int c = g16 * 8;
      float4 va0 = *(const float4*)&A3F[swzF(n, c)];
      float4 va1 = *(const float4*)&A3F[swzF(n, c + 4)];
      float4 vd0 = *(const float4*)&D3F[swzF(n, c)];
      float4 vd1 = *(const float4*)&D3F[swzF(n, c + 4)];
      float4 w0 = *(const float4*)&w4d[c];
      float4 w1 = *(const float4*)&w4d[c + 4];
      float sr = va0.x * w0.x + va0.y * w0.y + va0.z * w0.z + va0.w * w0.w +
                 va1.x * w1.x + va1.y * w1.y + va1.z * w1.z + va1.w * w1.w;
      float sd = vd0.x * w0.x + vd0.y * w0.y + vd0.z * w0.z + vd0.w * w0.w +
                 vd1.x * w1.x + vd1.y * w1.y + vd1.z * w1.z + vd1.w * w1.w;
      sr += __shfl_xor(sr, 1); sr += __shfl_xor(sr, 2);
      sr += __shfl_xor(sr, 4); sr += __shfl_xor(sr, 8);
      sd += __shfl_xor(sd, 1); sd += __shfl_xor(sd, 2);
      sd += __shfl_xor(sd, 4); sd += __shfl_xor(sd, 8);
      if (g16 == 0) {
        int ng = n0 + n;
        out_res[ng * 64 + d] = sr + b4[d];
        atomicAdd(&out_log[ng], logf(fabsf(sd) + 1e-8f));
      }
    }
  }
}

// ---------------- two-kernel fallback (R6 path) ------------------------------
__global__ __launch_bounds__(256)
void prep_kernel(const float* __restrict__ W1, const float* __restrict__ W2,
                 const float* __restrict__ W3, f16* __restrict__ wsf,
                 float* __restrict__ w1lg, float* __restrict__ out_log) {
  __shared__ float lds[64 * 132];
  const int d = blockIdx.x, sec = blockIdx.y, tid = threadIdx.x;
  f16* out = wsf + (size_t)d * PD;

  if (sec == 0) {
    const float* W1d = W1 + d * Hh * 65;
    const float4* g4 = (const float4*)W1d;
    for (int i = tid; i < 2080; i += 256) ((float4*)lds)[i] = g4[i];
    __syncthreads();
    for (int ci = tid; ci < 2048; ci += 256) {
      int hf = ci >> 10, rem = ci & 1023;
      int plane = rem >> 9, j = rem & 511;
      int r = j >> 3, sc = j & 7;
      int h = hf * 64 + r;
      int k0 = (sc ^ (r & 7)) << 3;
      const float* src = &lds[h * 65 + k0];
      f16x8 v;
#pragma unroll
      for (int e = 0; e < 8; e++) {
        float f = src[e];
        if (plane == 0) v[e] = (f16)f;
        else {
          f16 hi = (f16)f;
          v[e] = (f16)((f - (float)hi) * 2048.0f);
        }
      }
      *(f16x8*)&out[ci * 8] = v;
    }
    if (tid < 128) w1lg[d * Hh + tid] = lds[tid * 65 + 64];
    if (tid < 64) out_log[d * 64 + tid] = 0.f;
  } else {
    int w = (sec - 1) >> 1, hh = (sec - 1) & 1;
    const float* g = (w == 0 ? W2 : W3) + d * Hh * Hh + hh * 8192;
    const float4* g4 = (const float4*)g;
    for (int i = tid; i < 2048; i += 256) {
      int r = i >> 5, c4 = (i & 31) << 2;
      *(float4*)&lds[r * 132 + c4] = g4[i];
    }
    __syncthreads();
    f16* ob = out + 16384 + w * 32768 + hh * 16384;
    for (int ci = tid; ci < 2048; ci += 256) {
      int plane = ci >> 10, j = ci & 1023;
      int r = j >> 4, sc = j & 15;
      int k0 = (sc ^ (r & 15)) << 3;
      const float* src = &lds[r * 132 + k0];
      f16x8 v;
#pragma unroll
      for (int e = 0; e < 8; e++) {
        float f = src[e];
        if (plane == 0) v[e] = (f16)f;
        else {
          f16 hi = (f16)f;
          v[e] = (f16)((f - (float)hi) * 2048.0f);
        }
      }
      *(f16x8*)&ob[ci * 8] = v;
    }
  }
}

__global__ __launch_bounds__(512, 4)
void np_prior_fast(const float* __restrict__ x, const f16* __restrict__ wsw,
                   const float* __restrict__ w1lg,
                   const float* __restrict__ b1, const float* __restrict__ b2,
                   const float* __restrict__ b3, const float* __restrict__ W4,
                   const float* __restrict__ b4,
                   float* __restrict__ out_res, float* __restrict__ out_log) {
  __shared__ float4 smem[4096];
  f16* AH = (f16*)smem;
  f16* AL = AH + NT * 128;
  f16* DH = AL + NT * 128;
  f16* DL = DH + NT * 128;
  f16* Wreg = (f16*)((char*)smem + 32768);
  float* A3F = (float*)smem;
  float* D3F = (float*)((char*)smem + 16384);

  const int tid = threadIdx.x, d = blockIdx.y, n0 = blockIdx.x * NT;
  const int lane = tid & 63, wv = tid >> 6, l15 = lane & 15, quad = lane >> 4;
  const int nt = wv & 1, wq = wv >> 1;
  const int ra = nt * 16 + l15;
  const int hr = wq * 16 + l15;

  const f16* wd = wsw + (size_t)d * PD;
  const float* w1l = w1lg + d * Hh;
  const float* b1d = b1 + d * Hh;
  const f32x4 zero = {0.f, 0.f, 0.f, 0.f};

  cp_lds_async512(wd, Wreg, 16384, tid);
  {
    int n = tid >> 4, k4 = (tid & 15) << 2;
    int ng = n0 + n, bb = ng >> 8, tt = ng & 255;
    float4 v = *(const float4*)&x[(bb * 257 + tt) * 64 + k4];
    HL a = split(v.x), b = split(v.y), c = split(v.z), e = split(v.w);
    int o = swz(n, k4);
    *(f16x4*)&AH[o] = f16x4{a.h, b.h, c.h, e.h};
    *(f16x4*)&AL[o] = f16x4{a.l, b.l, c.l, e.l};
  }
  float xtv;
  {
    int ng = n0 + ra, bb = ng >> 8, tt = ng & 255;
    xtv = x[(bb * 257 + tt + 1) * 64 + d];
  }
  __syncthreads();

  f32x4 l1P[2], l1S[2];
#pragma unroll
  for (int hf = 0; hf < 2; hf++) {
    if (hf == 1) {
      __syncthreads();
      cp_lds_async512(wd + 8192, Wreg, 16384, tid);
      __syncthreads();
    }
    l1P[hf] = zero; l1S[hf] = zero;
#pragma unroll
    for (int kc = 0; kc < 2; kc++) {
      int ko = kc * 32 + quad * 8;
      f16x8 xh = *(const f16x8*)&AH[swz(ra, ko)];
      f16x8 xl = *(const f16x8*)&AL[swz(ra, ko)];
      f16x8 wh = *(const f16x8*)&Wreg[swzK64(hr, ko)];
      f16x8 wl = *(const f16x8*)&Wreg[4096 + swzK64(hr, ko)];
      l1P[hf] = MFMA(wh, xh, l1P[hf]);
      l1S[hf] = MFMA(wl, xh, l1S[hf]);
      l1S[hf] = MFMA(wh, xl, l1S[hf]);
    }
  }
  __syncthreads();
  cp_lds_async512(wd + 16384, Wreg, 32768, tid);

#pragma unroll
  for (int hf = 0; hf < 2; hf++) {
    int hb = hf * 64 + wq * 16 + quad * 4;
    float4 wv4 = *(const float4*)&w1l[hb];
    float4 bv4 = *(const float4*)&b1d[hb];
    f16x4 ah, al, dh, dl;
#pragma unroll
    for (int j = 0; j < 4; j++) {
      float w1j = (&wv4.x)[j];
      float p = l1P[hf][j] + l1S[hf][j] * INV2K + xtv * w1j + (&bv4.x)[j];
      float s = p > 0.f ? 1.f : SLP;
      HL av = split(p * s), dv = split(s * w1j);
      ah[j] = av.h; al[j] = av.l; dh[j] = dv.h; dl[j] = dv.l;
    }
    int o = swz(ra, hb);
    *(f16x4*)&AH[o] = ah; *(f16x4*)&AL[o] = al;
    *(f16x4*)&DH[o] = dh; *(f16x4*)&DL[o] = dl;
  }
  __syncthreads();

  f32x4 aP[2], aS[2], dP[2], dS[2];
#pragma unroll
  for (int hf = 0; hf < 2; hf++) {
    if (hf == 1) {
      __syncthreads();
      cp_lds_async512(wd + 32768, Wreg, 32768, tid);
      __syncthreads();
    }
    aP[hf] = zero; aS[hf] = zero; dP[hf] = zero; dS[hf] = zero;
    mid_half(AH, AL, DH, DL, Wreg, Wreg + 8192, ra, hr, quad,
             aP[hf], aS[hf], dP[hf], dS[hf]);
  }
  __syncthreads();
  cp_lds_async512(wd + 49152, Wreg, 32768, tid);

  {
    const float* b2d = b2 + d * Hh;
#pragma unroll
    for (int hf = 0; hf < 2; hf++) {
      int hb = hf * 64 + wq * 16 + quad * 4;
      float4 bv4 = *(const float4*)&b2d[hb];
      f16x4 ah, al, dh, dl;
#pragma unroll
      for (int j = 0; j < 4; j++) {
        float p = aP[hf][j] + aS[hf][j] * INV2K + (&bv4.x)[j];
        float s = p > 0.f ? 1.f : SLP;
        float dd = s * (dP[hf][j] + dS[hf][j] * INV2K);
        HL av = split(p * s), dv = split(dd);
        ah[j] = av.h; al[j] = av.l; dh[j] = dv.h; dl[j] = dv.l;
      }
      int o = swz(ra, hb);
      *(f16x4*)&AH[o] = ah; *(f16x4*)&AL[o] = al;
      *(f16x4*)&DH[o] = dh; *(f16x4*)&DL[o] = dl;
    }
  }
  __syncthreads();

#pragma unroll
  for (int hf = 0; hf < 2; hf++) {
    if (hf == 1) {
      __syncthreads();
      cp_lds_async512(wd + 65536, Wreg, 32768, tid);
      __syncthreads();
    }
    aP[hf] = zero; aS[hf] = zero; dP[hf] = zero; dS[hf] = zero;
    mid_half(AH, AL, DH, DL, Wreg, Wreg + 8192, ra, hr, quad,
             aP[hf], aS[hf], dP[hf], dS[hf]);
  }
  __syncthreads();

  {
    const float* b3d = b3 + d * Hh;
#pragma unroll
    for (int hf = 0; hf < 2; hf++) {
      int hb = hf * 64 + wq * 16 + quad * 4;
      float4 bv4 = *(const float4*)&b3d[hb];
      float4 pa, pd;
#pragma unroll
      for (int j = 0; j < 4; j++) {
        float p = aP[hf][j] + aS[hf][j] * INV2K + (&bv4.x)[j];
        float s = p > 0.f ? 1.f : SLP;
        (&pa.x)[j] = p * s;
        (&pd.x)[j] = s * (dP[hf][j] + dS[hf][j] * INV2K);
      }
      *(float4*)&A3F[swzF(ra, hb)] = pa;
      *(float4*)&D3F[swzF(ra, hb)] = pd;
    }
  }
  __syncthreads();

  {
    int n = tid >> 4, g16 = tid & 15;
    const float* w4d = W4 + d * Hh;
    int c = g16 * 8;
    float4 va0 = *(const float4*)&A3F[swzF(n, c)];
    float4 va1 = *(const float4*)&A3F[swzF(n, c + 4)];
    float4 vd0 = *(const float4*)&D3F[swzF(n, c)];
    float4 vd1 = *(const float4*)&D3F[swzF(n, c + 4)];
    float4 w0 = *(const float4*)&w4d[c];
    float4 w1 = *(const float4*)&w4d[c + 4];
    float sr = va0.x * w0.x + va0.y * w0.y + va0.z * w0.z + va0.w * w0.w +
               va1.x * w1.x + va1.y * w1.y + va1.z * w1.z + va1.w * w1.w;
    float sd = vd0.x * w0.x + vd0.y * w0.y + vd0.z * w0.z + vd0.w * w0.w +
               vd1.x * w1.x + vd1.y * w1.y + vd1.z * w1.z + vd1.w * w1.w;
    sr += __shfl_xor(sr, 1); sr += __shfl_xor(sr, 2);
    sr += __shfl_xor(sr, 4); sr += __shfl_xor(sr, 8);
    sd += __shfl_xor(sd, 1); sd += __shfl_xor(sd, 2);
    sd += __shfl_xor(sd, 4); sd += __shfl_xor(sd, 8);
    if (g16 == 0) {
      int ng = n0 + n;
      out_res[ng * 64 + d] = sr + b4[d];
      atomicAdd(&out_log[ng], logf(fabsf(sd) + 1e-8f));
    }
  }
}

extern "C" void kernel_launch(void* const* d_in, const int* in_sizes, int n_in,
                              void* d_out, int out_size, void* d_ws, size_t ws_size,
                              hipStream_t stream) {
  (void)in_sizes; (void)n_in; (void)out_size;
  const float* x  = (const float*)d_in[0];
  const float* W1 = (const float*)d_in[1];
  const float* b1 = (const float*)d_in[2];
  const float* W2 = (const float*)d_in[3];
  const float* b2 = (const float*)d_in[4];
  const float* W3 = (const float*)d_in[5];
  const float* b3 = (const float*)d_in[6];
  const float* W4 = (const float*)d_in[7];
  const float* b4 = (const float*)d_in[8];

  float* out_res = (float*)d_out;
  float* out_log = out_res + Nn * Dd;

  if (ws_size >= WS_NEEDED) {
    f16* wsf = (f16*)d_ws;
    float* w1lg = (float*)((char*)d_ws + W1L_OFF);

    // Size the cooperative grid by the runtime's own occupancy model so its
    // co-residency check passes by construction. (Pure host query — capture-safe.)
    int maxB = 0;
    hipError_t qerr = hipOccupancyMaxActiveBlocksPerMultiprocessor(
        &maxB, np_prior_coop, 512, 0);
    if (qerr == hipSuccess && maxB >= 1) {
      int gridB = maxB * 256;        // 256 CUs on MI355X
      if (gridB > 512) gridB = 512;  // 8192 % {256,512} == 0
      void* kargs[] = {(void*)&x,  (void*)&W1, (void*)&W2, (void*)&W3,
                       (void*)&b1, (void*)&b2, (void*)&b3, (void*)&W4,
                       (void*)&b4, (void*)&wsf, (void*)&w1lg,
                       (void*)&out_res, (void*)&out_log};
      hipError_t lerr = hipLaunchCooperativeKernel(
          np_prior_coop, dim3(gridB), dim3(512), kargs, 0u, stream);
      if (lerr == hipSuccess) return;
      // else fall through to the proven two-kernel path
    }
    prep_kernel<<<dim3(Dd, 5), 256, 0, stream>>>(W1, W2, W3, wsf, w1lg, out_log);
    dim3 grid(Nn / NT, Dd);
    np_prior_fast<<<grid, 512, 0, stream>>>(x, wsf, w1lg, b1, b2, b3, W4, b4,
                                            out_res, out_log);
  } else {
    // minimal no-ws path: zero log then reuse the fast kernel's math is not
    // possible without ws; harness always provides ws >= WS_NEEDED in practice.
    hipMemsetAsync(out_log, 0, Nn * sizeof(float), stream);
  }
}

// Round 10
// 249.335 us; speedup vs baseline: 1.7782x; 1.7782x over previous
//
#include <hip/hip_runtime.h>
#include <hip/hip_bf16.h>
#include <math.h>

typedef _Float16 f16;
typedef _Float16 f16x8 __attribute__((ext_vector_type(8)));
typedef _Float16 f16x4 __attribute__((ext_vector_type(4)));
typedef float f32x4 __attribute__((ext_vector_type(4)));

#define MFMA(a, b, c) __builtin_amdgcn_mfma_f32_16x16x32_f16((a), (b), (c), 0, 0, 0)

constexpr int Dd = 64;
constexpr int Hh = 128;
constexpr int Nn = 4096;
constexpr int NT = 32;
constexpr float SLP = 0.2f;
constexpr float INV2K = 1.0f / 2048.0f;

// Per-d f16 layout in d_ws:
//   [0,16384)     W1: h0 (hi 4096|lo 4096 swzK64), h1
//   [16384,49152) W2: h0 (hi 8192|lo 8192 swz), h1
//   [49152,81920) W3: h0, h1
constexpr int PD = 81920;
constexpr size_t W1L_OFF = (size_t)Dd * PD * 2;  // bytes; then w1last f32[64][128]
constexpr size_t WS_NEEDED = W1L_OFF + (size_t)Dd * Hh * 4;

__device__ __forceinline__ int swz(int r, int c) {
  return (r << 7) + ((((c >> 3) ^ (r & 15)) << 3) | (c & 7));
}
__device__ __forceinline__ int swzK64(int r, int c) {
  return (r << 6) + (((((c >> 3) ^ r) & 7) << 3) | (c & 7));
}
__device__ __forceinline__ int swzF(int n, int h) {
  return (n << 7) + ((((h >> 2) ^ n) & 31) << 2) + (h & 3);
}

struct HL { f16 h, l; };
__device__ __forceinline__ HL split(float v) {
  HL r;
  r.h = (f16)v;
  r.l = (f16)((v - (float)r.h) * 2048.0f);
  return r;
}

// Async contiguous global->LDS, 512 threads: nbytes multiple of 8192
__device__ __forceinline__ void cp_lds_async512(const void* g, void* l, int nbytes, int tid) {
  const int lane = tid & 63, wv = tid >> 6;
  for (int base = wv * 1024; base < nbytes; base += 8192) {
    __builtin_amdgcn_global_load_lds(
        (const __attribute__((address_space(1))) void*)((const char*)g + base + lane * 16),
        (__attribute__((address_space(3))) void*)((char*)l + base), 16, 0, 0);
  }
}

// ---------------- preprocess v4: one 16B chunk per thread --------------------
// 2560 blocks x 256 thr = 655360 threads = 655360 output chunks. 8 blocks/CU
// co-resident -> max memory-level parallelism vs cold-HBM latency.
// Mapping verified end-to-end in R9's cooperative run.
__global__ __launch_bounds__(256)
void prep_kernel(const float* __restrict__ W1, const float* __restrict__ W2,
                 const float* __restrict__ W3, f16* __restrict__ wsf,
                 float* __restrict__ w1lg, float* __restrict__ out_log) {
  const int gid = blockIdx.x * 256 + threadIdx.x;  // [0, 655360)
  // side tasks (first few blocks)
  if (gid < Dd * Hh) w1lg[gid] = W1[(gid >> 7) * 8320 + (gid & 127) * 65 + 64];
  if (gid < Nn) out_log[gid] = 0.f;

  const int d = gid / 10240;
  const int r = gid - d * 10240;
  f16* outd = wsf + (size_t)d * PD;
  float vv[8];
  f16* dst;
  int plane;
  if (r < 2048) {
    // W1 region (hi: swzK64 image, lo: same linear order)
    int rem = r & 1023;
    int hf = r >> 10;
    plane = rem >> 9;
    int j = rem & 511;
    int row = j >> 3, sc = j & 7;
    int h = hf * 64 + row;
    int k0 = (sc ^ (row & 7)) << 3;
    const float* src = W1 + d * 8320 + h * 65 + k0;  // 4B-aligned
#pragma unroll
    for (int e = 0; e < 8; e++) vv[e] = src[e];
    dst = outd + r * 8;
  } else {
    int r2 = r - 2048;
    int wsec = r2 >> 11;  // 0=W2h0 1=W2h1 2=W3h0 3=W3h1
    int rr = r2 & 2047;
    plane = rr >> 10;
    int j = rr & 1023;
    int row = j >> 4, sc = j & 15;
    int k0 = (sc ^ (row & 15)) << 3;
    const float* base = (wsec < 2 ? W2 : W3) + d * 16384 + (wsec & 1) * 8192;
    const float* src = base + row * 128 + k0;  // 32B-aligned
    float4 v0 = *(const float4*)src, v1 = *(const float4*)(src + 4);
    vv[0] = v0.x; vv[1] = v0.y; vv[2] = v0.z; vv[3] = v0.w;
    vv[4] = v1.x; vv[5] = v1.y; vv[6] = v1.z; vv[7] = v1.w;
    dst = outd + 16384 + (wsec >> 1) * 32768 + (wsec & 1) * 16384 + rr * 8;
  }
  if (plane) {
#pragma unroll
    for (int e = 0; e < 8; e++) {
      f16 hi = (f16)vv[e];
      vv[e] = (vv[e] - (float)hi) * 2048.0f;
    }
  }
  f16x8 o;
#pragma unroll
  for (int e = 0; e < 8; e++) o[e] = (f16)vv[e];
  *(f16x8*)dst = o;
}

// One W-half of a mid layer, one h-tile per wave. All operands from LDS.
__device__ __forceinline__ void mid_half(
    const f16* AH, const f16* AL, const f16* DH, const f16* DL,
    const f16* WH, const f16* WL, int ra, int hr, int quad,
    f32x4& aP, f32x4& aS, f32x4& dP, f32x4& dS) {
#pragma unroll
  for (int kc = 0; kc < 4; kc++) {
    int ko = kc * 32 + quad * 8;
    f16x8 xh = *(const f16x8*)&AH[swz(ra, ko)];
    f16x8 xl = *(const f16x8*)&AL[swz(ra, ko)];
    f16x8 yh = *(const f16x8*)&DH[swz(ra, ko)];
    f16x8 yl = *(const f16x8*)&DL[swz(ra, ko)];
    f16x8 wh = *(const f16x8*)&WH[swz(hr, ko)];
    f16x8 wl = *(const f16x8*)&WL[swz(hr, ko)];
    aP = MFMA(wh, xh, aP);
    aS = MFMA(wl, xh, aS);
    aS = MFMA(wh, xl, aS);
    dP = MFMA(wh, yh, dP);
    dS = MFMA(wl, yh, dS);
    dS = MFMA(wh, yl, dS);
  }
}

// 512 threads (8 waves). [R6 main kernel, byte-identical — 185 us verified]
__global__ __launch_bounds__(512, 4)
void np_prior_fast(const float* __restrict__ x, const f16* __restrict__ wsw,
                   const float* __restrict__ w1lg,
                   const float* __restrict__ b1, const float* __restrict__ b2,
                   const float* __restrict__ b3, const float* __restrict__ W4,
                   const float* __restrict__ b4,
                   float* __restrict__ out_res, float* __restrict__ out_log) {
  __shared__ float4 smem[4096];  // 64 KB
  f16* AH = (f16*)smem;
  f16* AL = AH + NT * 128;
  f16* DH = AL + NT * 128;
  f16* DL = DH + NT * 128;
  f16* Wreg = (f16*)((char*)smem + 32768);
  float* A3F = (float*)smem;
  float* D3F = (float*)((char*)smem + 16384);

  const int tid = threadIdx.x, d = blockIdx.y, n0 = blockIdx.x * NT;
  const int lane = tid & 63, wv = tid >> 6, l15 = lane & 15, quad = lane >> 4;
  const int nt = wv & 1, wq = wv >> 1;
  const int ra = nt * 16 + l15;
  const int hr = wq * 16 + l15;

  const f16* wd = wsw + (size_t)d * PD;
  const float* w1l = w1lg + d * Hh;
  const float* b1d = b1 + d * Hh;
  const f32x4 zero = {0.f, 0.f, 0.f, 0.f};

  cp_lds_async512(wd, Wreg, 16384, tid);
  {
    int n = tid >> 4, k4 = (tid & 15) << 2;
    int ng = n0 + n, bb = ng >> 8, tt = ng & 255;
    float4 v = *(const float4*)&x[(bb * 257 + tt) * 64 + k4];
    HL a = split(v.x), b = split(v.y), c = split(v.z), e = split(v.w);
    int o = swz(n, k4);
    *(f16x4*)&AH[o] = f16x4{a.h, b.h, c.h, e.h};
    *(f16x4*)&AL[o] = f16x4{a.l, b.l, c.l, e.l};
  }
  float xtv;
  {
    int ng = n0 + ra, bb = ng >> 8, tt = ng & 255;
    xtv = x[(bb * 257 + tt + 1) * 64 + d];
  }
  __syncthreads();

  // ---- Layer 1 (K=64)
  f32x4 l1P[2], l1S[2];
#pragma unroll
  for (int hf = 0; hf < 2; hf++) {
    if (hf == 1) {
      __syncthreads();
      cp_lds_async512(wd + 8192, Wreg, 16384, tid);
      __syncthreads();
    }
    l1P[hf] = zero; l1S[hf] = zero;
#pragma unroll
    for (int kc = 0; kc < 2; kc++) {
      int ko = kc * 32 + quad * 8;
      f16x8 xh = *(const f16x8*)&AH[swz(ra, ko)];
      f16x8 xl = *(const f16x8*)&AL[swz(ra, ko)];
      f16x8 wh = *(const f16x8*)&Wreg[swzK64(hr, ko)];
      f16x8 wl = *(const f16x8*)&Wreg[4096 + swzK64(hr, ko)];
      l1P[hf] = MFMA(wh, xh, l1P[hf]);
      l1S[hf] = MFMA(wl, xh, l1S[hf]);
      l1S[hf] = MFMA(wh, xl, l1S[hf]);
    }
  }
  __syncthreads();
  cp_lds_async512(wd + 16384, Wreg, 32768, tid);  // W2-h0

  // ---- L1 epilogue
#pragma unroll
  for (int hf = 0; hf < 2; hf++) {
    int hb = hf * 64 + wq * 16 + quad * 4;
    float4 wv4 = *(const float4*)&w1l[hb];
    float4 bv4 = *(const float4*)&b1d[hb];
    f16x4 ah, al, dh, dl;
#pragma unroll
    for (int j = 0; j < 4; j++) {
      float w1j = (&wv4.x)[j];
      float p = l1P[hf][j] + l1S[hf][j] * INV2K + xtv * w1j + (&bv4.x)[j];
      float s = p > 0.f ? 1.f : SLP;
      HL av = split(p * s), dv = split(s * w1j);
      ah[j] = av.h; al[j] = av.l; dh[j] = dv.h; dl[j] = dv.l;
    }
    int o = swz(ra, hb);
    *(f16x4*)&AH[o] = ah; *(f16x4*)&AL[o] = al;
    *(f16x4*)&DH[o] = dh; *(f16x4*)&DL[o] = dl;
  }
  __syncthreads();

  // ---- Layer 2
  f32x4 aP[2], aS[2], dP[2], dS[2];
#pragma unroll
  for (int hf = 0; hf < 2; hf++) {
    if (hf == 1) {
      __syncthreads();
      cp_lds_async512(wd + 32768, Wreg, 32768, tid);  // W2-h1
      __syncthreads();
    }
    aP[hf] = zero; aS[hf] = zero; dP[hf] = zero; dS[hf] = zero;
    mid_half(AH, AL, DH, DL, Wreg, Wreg + 8192, ra, hr, quad,
             aP[hf], aS[hf], dP[hf], dS[hf]);
  }
  __syncthreads();
  cp_lds_async512(wd + 49152, Wreg, 32768, tid);  // W3-h0

  // ---- L2 epilogue
  {
    const float* b2d = b2 + d * Hh;
#pragma unroll
    for (int hf = 0; hf < 2; hf++) {
      int hb = hf * 64 + wq * 16 + quad * 4;
      float4 bv4 = *(const float4*)&b2d[hb];
      f16x4 ah, al, dh, dl;
#pragma unroll
      for (int j = 0; j < 4; j++) {
        float p = aP[hf][j] + aS[hf][j] * INV2K + (&bv4.x)[j];
        float s = p > 0.f ? 1.f : SLP;
        float dd = s * (dP[hf][j] + dS[hf][j] * INV2K);
        HL av = split(p * s), dv = split(dd);
        ah[j] = av.h; al[j] = av.l; dh[j] = dv.h; dl[j] = dv.l;
      }
      int o = swz(ra, hb);
      *(f16x4*)&AH[o] = ah; *(f16x4*)&AL[o] = al;
      *(f16x4*)&DH[o] = dh; *(f16x4*)&DL[o] = dl;
    }
  }
  __syncthreads();

  // ---- Layer 3
#pragma unroll
  for (int hf = 0; hf < 2; hf++) {
    if (hf == 1) {
      __syncthreads();
      cp_lds_async512(wd + 65536, Wreg, 32768, tid);  // W3-h1
      __syncthreads();
    }
    aP[hf] = zero; aS[hf] = zero; dP[hf] = zero; dS[hf] = zero;
    mid_half(AH, AL, DH, DL, Wreg, Wreg + 8192, ra, hr, quad,
             aP[hf], aS[hf], dP[hf], dS[hf]);
  }
  __syncthreads();

  // ---- L3 epilogue -> swizzled f32 overlay
  {
    const float* b3d = b3 + d * Hh;
#pragma unroll
    for (int hf = 0; hf < 2; hf++) {
      int hb = hf * 64 + wq * 16 + quad * 4;
      float4 bv4 = *(const float4*)&b3d[hb];
      float4 pa, pd;
#pragma unroll
      for (int j = 0; j < 4; j++) {
        float p = aP[hf][j] + aS[hf][j] * INV2K + (&bv4.x)[j];
        float s = p > 0.f ? 1.f : SLP;
        (&pa.x)[j] = p * s;
        (&pd.x)[j] = s * (dP[hf][j] + dS[hf][j] * INV2K);
      }
      *(float4*)&A3F[swzF(ra, hb)] = pa;
      *(float4*)&D3F[swzF(ra, hb)] = pd;
    }
  }
  __syncthreads();

  // ---- Layer 4
  {
    int n = tid >> 4, g16 = tid & 15;
    const float* w4d = W4 + d * Hh;
    int c = g16 * 8;
    float4 va0 = *(const float4*)&A3F[swzF(n, c)];
    float4 va1 = *(const float4*)&A3F[swzF(n, c + 4)];
    float4 vd0 = *(const float4*)&D3F[swzF(n, c)];
    float4 vd1 = *(const float4*)&D3F[swzF(n, c + 4)];
    float4 w0 = *(const float4*)&w4d[c];
    float4 w1 = *(const float4*)&w4d[c + 4];
    float sr = va0.x * w0.x + va0.y * w0.y + va0.z * w0.z + va0.w * w0.w +
               va1.x * w1.x + va1.y * w1.y + va1.z * w1.z + va1.w * w1.w;
    float sd = vd0.x * w0.x + vd0.y * w0.y + vd0.z * w0.z + vd0.w * w0.w +
               vd1.x * w1.x + vd1.y * w1.y + vd1.z * w1.z + vd1.w * w1.w;
    sr += __shfl_xor(sr, 1); sr += __shfl_xor(sr, 2);
    sr += __shfl_xor(sr, 4); sr += __shfl_xor(sr, 8);
    sd += __shfl_xor(sd, 1); sd += __shfl_xor(sd, 2);
    sd += __shfl_xor(sd, 4); sd += __shfl_xor(sd, 8);
    if (g16 == 0) {
      int ng = n0 + n;
      out_res[ng * 64 + d] = sr + b4[d];
      atomicAdd(&out_log[ng], logf(fabsf(sd) + 1e-8f));
    }
  }
}

// ---------------- fallback (no-ws path, 256 threads) -------------------------
__device__ __forceinline__ void stage_wf(f16* WH, f16* WL,
                                         const float* __restrict__ g, int tid) {
  for (int i = tid; i < 2048; i += 256) {
    int h = i >> 5, k4 = (i & 31) << 2;
    float4 v = ((const float4*)g)[i];
    HL a = split(v.x), b = split(v.y), c = split(v.z), e = split(v.w);
    int o = swz(h, k4);
    *(f16x4*)&WH[o] = f16x4{a.h, b.h, c.h, e.h};
    *(f16x4*)&WL[o] = f16x4{a.l, b.l, c.l, e.l};
  }
}

__device__ __forceinline__ void mid_mfma_half(
    const f16* AH, const f16* AL, const f16* DH, const f16* DL,
    const f16* WH, const f16* WL, int nt, int wq, int l15, int quad,
    f32x4* aP, f32x4* aS, f32x4* dP, f32x4* dS) {
#pragma unroll
  for (int kc = 0; kc < 4; kc++) {
    int ko = kc * 32 + quad * 8;
    int ra = nt * 16 + l15;
    f16x8 xh = *(const f16x8*)&AH[swz(ra, ko)];
    f16x8 xl = *(const f16x8*)&AL[swz(ra, ko)];
    f16x8 yh = *(const f16x8*)&DH[swz(ra, ko)];
    f16x8 yl = *(const f16x8*)&DL[swz(ra, ko)];
#pragma unroll
    for (int c2 = 0; c2 < 2; c2++) {
      int hr = (2 * wq + c2) * 16 + l15;
      f16x8 wh = *(const f16x8*)&WH[swz(hr, ko)];
      f16x8 wl = *(const f16x8*)&WL[swz(hr, ko)];
      aP[c2] = MFMA(wh, xh, aP[c2]);
      aS[c2] = MFMA(wl, xh, aS[c2]);
      aS[c2] = MFMA(wh, xl, aS[c2]);
      dP[c2] = MFMA(wh, yh, dP[c2]);
      dS[c2] = MFMA(wl, yh, dS[c2]);
      dS[c2] = MFMA(wh, yl, dS[c2]);
    }
  }
}

__global__ __launch_bounds__(256, 2)
void np_prior_fb(const float* __restrict__ x,
                 const float* __restrict__ W1, const float* __restrict__ b1,
                 const float* __restrict__ W2, const float* __restrict__ b2,
                 const float* __restrict__ W3, const float* __restrict__ b3,
                 const float* __restrict__ W4, const float* __restrict__ b4,
                 float* __restrict__ out_res, float* __restrict__ out_log) {
  __shared__ float4 smem[4096];
  f16* AH = (f16*)smem;
  f16* AL = AH + NT * 128;
  f16* DH = AL + NT * 128;
  f16* DL = DH + NT * 128;
  f16* WHp = (f16*)((char*)smem + 32768);
  f16* WLp = WHp + 64 * 128;
  float* A3F = (float*)smem;
  float* D3F = (float*)((char*)smem + 16384);

  const int tid = threadIdx.x, d = blockIdx.y, n0 = blockIdx.x * NT;
  const int lane = tid & 63, wv = tid >> 6, l15 = lane & 15, quad = lane >> 4;
  const int nt = wv & 1, wq = wv >> 1;

  const float* W1d = W1 + d * Hh * 65;
  const float* b1d = b1 + d * Hh;
  const f32x4 zero = {0.f, 0.f, 0.f, 0.f};

  for (int i = tid; i < NT * 16; i += 256) {
    int n = i >> 4, k4 = (i & 15) << 2;
    int ng = n0 + n, bb = ng >> 8, tt = ng & 255;
    float4 v = *(const float4*)&x[(bb * 257 + tt) * 64 + k4];
    HL a = split(v.x), b = split(v.y), c = split(v.z), e = split(v.w);
    int o = swz(n, k4);
    *(f16x4*)&AH[o] = f16x4{a.h, b.h, c.h, e.h};
    *(f16x4*)&AL[o] = f16x4{a.l, b.l, c.l, e.l};
  }
  float xtv;
  {
    int ng = n0 + nt * 16 + l15, bb = ng >> 8, tt = ng & 255;
    xtv = x[(bb * 257 + tt + 1) * 64 + d];
  }
  for (int i = tid; i < 64 * 64; i += 256) {
    int h = i >> 6, k = i & 63;
    HL s = split(W1d[h * 65 + k]);
    int o = swz(h, k);
    WHp[o] = s.h; WLp[o] = s.l;
  }
  __syncthreads();

  f32x4 l1P[2][2], l1S[2][2];
  for (int hf = 0; hf < 2; hf++) {
    if (hf == 1) {
      __syncthreads();
      for (int i = tid; i < 64 * 64; i += 256) {
        int h = i >> 6, k = i & 63;
        HL s = split(W1d[(64 + h) * 65 + k]);
        int o = swz(h, k);
        WHp[o] = s.h; WLp[o] = s.l;
      }
      __syncthreads();
    }
    l1P[hf][0] = zero; l1P[hf][1] = zero;
    l1S[hf][0] = zero; l1S[hf][1] = zero;
#pragma unroll
    for (int kc = 0; kc < 2; kc++) {
      int ko = kc * 32 + quad * 8;
      f16x8 xh = *(const f16x8*)&AH[swz(nt * 16 + l15, ko)];
      f16x8 xl = *(const f16x8*)&AL[swz(nt * 16 + l15, ko)];
#pragma unroll
      for (int c2 = 0; c2 < 2; c2++) {
        int hr = (2 * wq + c2) * 16 + l15;
        f16x8 wh = *(const f16x8*)&WHp[swz(hr, ko)];
        f16x8 wl = *(const f16x8*)&WLp[swz(hr, ko)];
        l1P[hf][c2] = MFMA(wh, xh, l1P[hf][c2]);
        l1S[hf][c2] = MFMA(wl, xh, l1S[hf][c2]);
        l1S[hf][c2] = MFMA(wh, xl, l1S[hf][c2]);
      }
    }
  }
  __syncthreads();

  {
    int n = nt * 16 + l15;
#pragma unroll
    for (int hf = 0; hf < 2; hf++)
#pragma unroll
      for (int c2 = 0; c2 < 2; c2++) {
        int hb = hf * 64 + (2 * wq + c2) * 16 + quad * 4;
        f16x4 ah, al, dh, dl;
#pragma unroll
        for (int j = 0; j < 4; j++) {
          int h = hb + j;
          float w1j = W1d[h * 65 + 64];
          float p = l1P[hf][c2][j] + l1S[hf][c2][j] * INV2K + xtv * w1j + b1d[h];
          float s = p > 0.f ? 1.f : SLP;
          HL av = split(p * s), dv = split(s * w1j);
          ah[j] = av.h; al[j] = av.l; dh[j] = dv.h; dl[j] = dv.l;
        }
        int o = swz(n, hb);
        *(f16x4*)&AH[o] = ah; *(f16x4*)&AL[o] = al;
        *(f16x4*)&DH[o] = dh; *(f16x4*)&DL[o] = dl;
      }
  }
  stage_wf(WHp, WLp, W2 + d * Hh * Hh, tid);
  __syncthreads();

  f32x4 aP[2][2], aS[2][2], dP[2][2], dS[2][2];
  for (int hf = 0; hf < 2; hf++) {
    if (hf == 1) {
      __syncthreads();
      stage_wf(WHp, WLp, W2 + d * Hh * Hh + 64 * 128, tid);
      __syncthreads();
    }
    aP[hf][0] = zero; aP[hf][1] = zero; aS[hf][0] = zero; aS[hf][1] = zero;
    dP[hf][0] = zero; dP[hf][1] = zero; dS[hf][0] = zero; dS[hf][1] = zero;
    mid_mfma_half(AH, AL, DH, DL, WHp, WLp, nt, wq, l15, quad,
                  aP[hf], aS[hf], dP[hf], dS[hf]);
  }
  __syncthreads();

  {
    const float* b2d = b2 + d * Hh;
    int n = nt * 16 + l15;
#pragma unroll
    for (int hf = 0; hf < 2; hf++)
#pragma unroll
      for (int c2 = 0; c2 < 2; c2++) {
        int hb = hf * 64 + (2 * wq + c2) * 16 + quad * 4;
        f16x4 ah, al, dh, dl;
#pragma unroll
        for (int j = 0; j < 4; j++) {
          int h = hb + j;
          float p = aP[hf][c2][j] + aS[hf][c2][j] * INV2K + b2d[h];
          float s = p > 0.f ? 1.f : SLP;
          float dd = s * (dP[hf][c2][j] + dS[hf][c2][j] * INV2K);
          HL av = split(p * s), dv = split(dd);
          ah[j] = av.h; al[j] = av.l; dh[j] = dv.h; dl[j] = dv.l;
        }
        int o = swz(n, hb);
        *(f16x4*)&AH[o] = ah; *(f16x4*)&AL[o] = al;
        *(f16x4*)&DH[o] = dh; *(f16x4*)&DL[o] = dl;
      }
  }
  stage_wf(WHp, WLp, W3 + d * Hh * Hh, tid);
  __syncthreads();

  for (int hf = 0; hf < 2; hf++) {
    if (hf == 1) {
      __syncthreads();
      stage_wf(WHp, WLp, W3 + d * Hh * Hh + 64 * 128, tid);
      __syncthreads();
    }
    aP[hf][0] = zero; aP[hf][1] = zero; aS[hf][0] = zero; aS[hf][1] = zero;
    dP[hf][0] = zero; dP[hf][1] = zero; dS[hf][0] = zero; dS[hf][1] = zero;
    mid_mfma_half(AH, AL, DH, DL, WHp, WLp, nt, wq, l15, quad,
                  aP[hf], aS[hf], dP[hf], dS[hf]);
  }
  __syncthreads();

  {
    const float* b3d = b3 + d * Hh;
    int n = nt * 16 + l15;
#pragma unroll
    for (int hf = 0; hf < 2; hf++)
#pragma unroll
      for (int c2 = 0; c2 < 2; c2++) {
        int hb = hf * 64 + (2 * wq + c2) * 16 + quad * 4;
        float4 pa, pd;
#pragma unroll
        for (int j = 0; j < 4; j++) {
          int h = hb + j;
          float p = aP[hf][c2][j] + aS[hf][c2][j] * INV2K + b3d[h];
          float s = p > 0.f ? 1.f : SLP;
          (&pa.x)[j] = p * s;
          (&pd.x)[j] = s * (dP[hf][c2][j] + dS[hf][c2][j] * INV2K);
        }
        *(float4*)&A3F[swzF(n, hb)] = pa;
        *(float4*)&D3F[swzF(n, hb)] = pd;
      }
  }
  __syncthreads();

  {
    int n = tid >> 3, oct = tid & 7;
    const float* w4d = W4 + d * Hh;
    float sr = 0.f, sd = 0.f;
#pragma unroll
    for (int i = 0; i < 4; i++) {
      int c = oct * 16 + i * 4;
      float4 va = *(const float4*)&A3F[swzF(n, c)];
      float4 vd = *(const float4*)&D3F[swzF(n, c)];
      float4 w = *(const float4*)&w4d[c];
      sr += va.x * w.x + va.y * w.y + va.z * w.z + va.w * w.w;
      sd += vd.x * w.x + vd.y * w.y + vd.z * w.z + vd.w * w.w;
    }
    sr += __shfl_xor(sr, 1); sr += __shfl_xor(sr, 2); sr += __shfl_xor(sr, 4);
    sd += __shfl_xor(sd, 1); sd += __shfl_xor(sd, 2); sd += __shfl_xor(sd, 4);
    if (oct == 0) {
      int ng = n0 + n;
      out_res[ng * 64 + d] = sr + b4[d];
      atomicAdd(&out_log[ng], logf(fabsf(sd) + 1e-8f));
    }
  }
}

extern "C" void kernel_launch(void* const* d_in, const int* in_sizes, int n_in,
                              void* d_out, int out_size, void* d_ws, size_t ws_size,
                              hipStream_t stream) {
  (void)in_sizes; (void)n_in; (void)out_size;
  const float* x  = (const float*)d_in[0];
  const float* W1 = (const float*)d_in[1];
  const float* b1 = (const float*)d_in[2];
  const float* W2 = (const float*)d_in[3];
  const float* b2 = (const float*)d_in[4];
  const float* W3 = (const float*)d_in[5];
  const float* b3 = (const float*)d_in[6];
  const float* W4 = (const float*)d_in[7];
  const float* b4 = (const float*)d_in[8];

  float* out_res = (float*)d_out;
  float* out_log = out_res + Nn * Dd;

  if (ws_size >= WS_NEEDED) {
    f16* wsf = (f16*)d_ws;
    float* w1lg = (float*)((char*)d_ws + W1L_OFF);
    // one output chunk per thread: 655360 chunks / 256 = 2560 blocks
    prep_kernel<<<2560, 256, 0, stream>>>(W1, W2, W3, wsf, w1lg, out_log);
    dim3 grid(Nn / NT, Dd);
    np_prior_fast<<<grid, 512, 0, stream>>>(x, wsf, w1lg, b1, b2, b3, W4, b4,
                                            out_res, out_log);
  } else {
    hipMemsetAsync(out_log, 0, Nn * sizeof(float), stream);
    dim3 grid(Nn / NT, Dd);
    np_prior_fb<<<grid, 256, 0, stream>>>(x, W1, b1, W2, b2, W3, b3, W4, b4,
                                          out_res, out_log);
  }
}

// Round 11
// 234.752 us; speedup vs baseline: 1.8887x; 1.0621x over previous
//
#include <hip/hip_runtime.h>
#include <hip/hip_bf16.h>
#include <math.h>

typedef _Float16 f16;
typedef _Float16 f16x8 __attribute__((ext_vector_type(8)));
typedef _Float16 f16x4 __attribute__((ext_vector_type(4)));
typedef float f32x4 __attribute__((ext_vector_type(4)));

#define MFMA(a, b, c) __builtin_amdgcn_mfma_f32_16x16x32_f16((a), (b), (c), 0, 0, 0)

constexpr int Dd = 64;
constexpr int Hh = 128;
constexpr int Nn = 4096;
constexpr int NT = 32;
constexpr float SLP = 0.2f;
constexpr float INV2K = 1.0f / 2048.0f;

// Per-d f16 layout in d_ws:
//   [0,16384)     W1: h0 (hi 4096|lo 4096 swzK64), h1
//   [16384,49152) W2: h0 (hi 8192|lo 8192 swz), h1
//   [49152,81920) W3: h0, h1
constexpr int PD = 81920;
constexpr size_t W1L_OFF = (size_t)Dd * PD * 2;  // bytes; then w1last f32[64][128]
constexpr size_t WS_NEEDED = W1L_OFF + (size_t)Dd * Hh * 4;

__device__ __forceinline__ int swz(int r, int c) {
  return (r << 7) + ((((c >> 3) ^ (r & 15)) << 3) | (c & 7));
}
__device__ __forceinline__ int swzK64(int r, int c) {
  return (r << 6) + (((((c >> 3) ^ r) & 7) << 3) | (c & 7));
}
__device__ __forceinline__ int swzF(int n, int h) {
  return (n << 7) + ((((h >> 2) ^ n) & 31) << 2) + (h & 3);
}

struct HL { f16 h, l; };
__device__ __forceinline__ HL split(float v) {
  HL r;
  r.h = (f16)v;
  r.l = (f16)((v - (float)r.h) * 2048.0f);
  return r;
}

// Async contiguous global->LDS, 512 threads: nbytes multiple of 8192
__device__ __forceinline__ void cp_lds_async512(const void* g, void* l, int nbytes, int tid) {
  const int lane = tid & 63, wv = tid >> 6;
  for (int base = wv * 1024; base < nbytes; base += 8192) {
    __builtin_amdgcn_global_load_lds(
        (const __attribute__((address_space(1))) void*)((const char*)g + base + lane * 16),
        (__attribute__((address_space(3))) void*)((char*)l + base), 16, 0, 0);
  }
}

// ---------------- preprocess v4: one 16B chunk per thread (R10, verified) ----
__global__ __launch_bounds__(256)
void prep_kernel(const float* __restrict__ W1, const float* __restrict__ W2,
                 const float* __restrict__ W3, f16* __restrict__ wsf,
                 float* __restrict__ w1lg, float* __restrict__ out_log) {
  const int gid = blockIdx.x * 256 + threadIdx.x;  // [0, 655360)
  if (gid < Dd * Hh) w1lg[gid] = W1[(gid >> 7) * 8320 + (gid & 127) * 65 + 64];
  if (gid < Nn) out_log[gid] = 0.f;

  const int d = gid / 10240;
  const int r = gid - d * 10240;
  f16* outd = wsf + (size_t)d * PD;
  float vv[8];
  f16* dst;
  int plane;
  if (r < 2048) {
    int rem = r & 1023;
    int hf = r >> 10;
    plane = rem >> 9;
    int j = rem & 511;
    int row = j >> 3, sc = j & 7;
    int h = hf * 64 + row;
    int k0 = (sc ^ (row & 7)) << 3;
    const float* src = W1 + d * 8320 + h * 65 + k0;
#pragma unroll
    for (int e = 0; e < 8; e++) vv[e] = src[e];
    dst = outd + r * 8;
  } else {
    int r2 = r - 2048;
    int wsec = r2 >> 11;  // 0=W2h0 1=W2h1 2=W3h0 3=W3h1
    int rr = r2 & 2047;
    plane = rr >> 10;
    int j = rr & 1023;
    int row = j >> 4, sc = j & 15;
    int k0 = (sc ^ (row & 15)) << 3;
    const float* base = (wsec < 2 ? W2 : W3) + d * 16384 + (wsec & 1) * 8192;
    const float* src = base + row * 128 + k0;
    float4 v0 = *(const float4*)src, v1 = *(const float4*)(src + 4);
    vv[0] = v0.x; vv[1] = v0.y; vv[2] = v0.z; vv[3] = v0.w;
    vv[4] = v1.x; vv[5] = v1.y; vv[6] = v1.z; vv[7] = v1.w;
    dst = outd + 16384 + (wsec >> 1) * 32768 + (wsec & 1) * 16384 + rr * 8;
  }
  if (plane) {
#pragma unroll
    for (int e = 0; e < 8; e++) {
      f16 hi = (f16)vv[e];
      vv[e] = (vv[e] - (float)hi) * 2048.0f;
    }
  }
  f16x8 o;
#pragma unroll
  for (int e = 0; e < 8; e++) o[e] = (f16)vv[e];
  *(f16x8*)dst = o;
}

// 512 threads (8 waves). R11: act operand fragments hoisted to registers once
// per layer (were re-read from LDS for each W-half) — LDS b128 traffic
// 112 -> 76 per wave. Otherwise identical to the verified R6/R10 body.
__global__ __launch_bounds__(512, 4)
void np_prior_fast(const float* __restrict__ x, const f16* __restrict__ wsw,
                   const float* __restrict__ w1lg,
                   const float* __restrict__ b1, const float* __restrict__ b2,
                   const float* __restrict__ b3, const float* __restrict__ W4,
                   const float* __restrict__ b4,
                   float* __restrict__ out_res, float* __restrict__ out_log) {
  __shared__ float4 smem[4096];  // 64 KB
  f16* AH = (f16*)smem;
  f16* AL = AH + NT * 128;
  f16* DH = AL + NT * 128;
  f16* DL = DH + NT * 128;
  f16* Wreg = (f16*)((char*)smem + 32768);
  float* A3F = (float*)smem;
  float* D3F = (float*)((char*)smem + 16384);

  const int tid = threadIdx.x, d = blockIdx.y, n0 = blockIdx.x * NT;
  const int lane = tid & 63, wv = tid >> 6, l15 = lane & 15, quad = lane >> 4;
  const int nt = wv & 1, wq = wv >> 1;
  const int ra = nt * 16 + l15;
  const int hr = wq * 16 + l15;

  const f16* wd = wsw + (size_t)d * PD;
  const float* w1l = w1lg + d * Hh;
  const float* b1d = b1 + d * Hh;
  const f32x4 zero = {0.f, 0.f, 0.f, 0.f};

  cp_lds_async512(wd, Wreg, 16384, tid);
  {
    int n = tid >> 4, k4 = (tid & 15) << 2;
    int ng = n0 + n, bb = ng >> 8, tt = ng & 255;
    float4 v = *(const float4*)&x[(bb * 257 + tt) * 64 + k4];
    HL a = split(v.x), b = split(v.y), c = split(v.z), e = split(v.w);
    int o = swz(n, k4);
    *(f16x4*)&AH[o] = f16x4{a.h, b.h, c.h, e.h};
    *(f16x4*)&AL[o] = f16x4{a.l, b.l, c.l, e.l};
  }
  float xtv;
  {
    int ng = n0 + ra, bb = ng >> 8, tt = ng & 255;
    xtv = x[(bb * 257 + tt + 1) * 64 + d];
  }
  __syncthreads();

  // ---- Layer 1 (K=64): act frags hoisted (read once, used in both halves)
  f32x4 l1P[2], l1S[2];
  {
    f16x8 l1xh[2], l1xl[2];
#pragma unroll
    for (int kc = 0; kc < 2; kc++) {
      int ko = kc * 32 + quad * 8;
      l1xh[kc] = *(const f16x8*)&AH[swz(ra, ko)];
      l1xl[kc] = *(const f16x8*)&AL[swz(ra, ko)];
    }
#pragma unroll
    for (int hf = 0; hf < 2; hf++) {
      if (hf == 1) {
        __syncthreads();
        cp_lds_async512(wd + 8192, Wreg, 16384, tid);
        __syncthreads();
      }
      l1P[hf] = zero; l1S[hf] = zero;
#pragma unroll
      for (int kc = 0; kc < 2; kc++) {
        int ko = kc * 32 + quad * 8;
        f16x8 wh = *(const f16x8*)&Wreg[swzK64(hr, ko)];
        f16x8 wl = *(const f16x8*)&Wreg[4096 + swzK64(hr, ko)];
        l1P[hf] = MFMA(wh, l1xh[kc], l1P[hf]);
        l1S[hf] = MFMA(wl, l1xh[kc], l1S[hf]);
        l1S[hf] = MFMA(wh, l1xl[kc], l1S[hf]);
      }
    }
  }
  __syncthreads();
  cp_lds_async512(wd + 16384, Wreg, 32768, tid);  // W2-h0

  // ---- L1 epilogue
#pragma unroll
  for (int hf = 0; hf < 2; hf++) {
    int hb = hf * 64 + wq * 16 + quad * 4;
    float4 wv4 = *(const float4*)&w1l[hb];
    float4 bv4 = *(const float4*)&b1d[hb];
    f16x4 ah, al, dh, dl;
#pragma unroll
    for (int j = 0; j < 4; j++) {
      float w1j = (&wv4.x)[j];
      float p = l1P[hf][j] + l1S[hf][j] * INV2K + xtv * w1j + (&bv4.x)[j];
      float s = p > 0.f ? 1.f : SLP;
      HL av = split(p * s), dv = split(s * w1j);
      ah[j] = av.h; al[j] = av.l; dh[j] = dv.h; dl[j] = dv.l;
    }
    int o = swz(ra, hb);
    *(f16x4*)&AH[o] = ah; *(f16x4*)&AL[o] = al;
    *(f16x4*)&DH[o] = dh; *(f16x4*)&DL[o] = dl;
  }
  __syncthreads();

  // ---- Layer 2: act frags hoisted for the whole layer (16 b128)
  f32x4 aP[2], aS[2], dP[2], dS[2];
  {
    f16x8 axh[4], axl[4], ayh[4], ayl[4];
#pragma unroll
    for (int kc = 0; kc < 4; kc++) {
      int ko = kc * 32 + quad * 8;
      axh[kc] = *(const f16x8*)&AH[swz(ra, ko)];
      axl[kc] = *(const f16x8*)&AL[swz(ra, ko)];
      ayh[kc] = *(const f16x8*)&DH[swz(ra, ko)];
      ayl[kc] = *(const f16x8*)&DL[swz(ra, ko)];
    }
#pragma unroll
    for (int hf = 0; hf < 2; hf++) {
      if (hf == 1) {
        __syncthreads();
        cp_lds_async512(wd + 32768, Wreg, 32768, tid);  // W2-h1
        __syncthreads();
      }
      aP[hf] = zero; aS[hf] = zero; dP[hf] = zero; dS[hf] = zero;
#pragma unroll
      for (int kc = 0; kc < 4; kc++) {
        int ko = kc * 32 + quad * 8;
        f16x8 wh = *(const f16x8*)&Wreg[swz(hr, ko)];
        f16x8 wl = *(const f16x8*)&Wreg[8192 + swz(hr, ko)];
        aP[hf] = MFMA(wh, axh[kc], aP[hf]);
        aS[hf] = MFMA(wl, axh[kc], aS[hf]);
        aS[hf] = MFMA(wh, axl[kc], aS[hf]);
        dP[hf] = MFMA(wh, ayh[kc], dP[hf]);
        dS[hf] = MFMA(wl, ayh[kc], dS[hf]);
        dS[hf] = MFMA(wh, ayl[kc], dS[hf]);
      }
    }
  }
  __syncthreads();
  cp_lds_async512(wd + 49152, Wreg, 32768, tid);  // W3-h0

  // ---- L2 epilogue
  {
    const float* b2d = b2 + d * Hh;
#pragma unroll
    for (int hf = 0; hf < 2; hf++) {
      int hb = hf * 64 + wq * 16 + quad * 4;
      float4 bv4 = *(const float4*)&b2d[hb];
      f16x4 ah, al, dh, dl;
#pragma unroll
      for (int j = 0; j < 4; j++) {
        float p = aP[hf][j] + aS[hf][j] * INV2K + (&bv4.x)[j];
        float s = p > 0.f ? 1.f : SLP;
        float dd = s * (dP[hf][j] + dS[hf][j] * INV2K);
        HL av = split(p * s), dv = split(dd);
        ah[j] = av.h; al[j] = av.l; dh[j] = dv.h; dl[j] = dv.l;
      }
      int o = swz(ra, hb);
      *(f16x4*)&AH[o] = ah; *(f16x4*)&AL[o] = al;
      *(f16x4*)&DH[o] = dh; *(f16x4*)&DL[o] = dl;
    }
  }
  __syncthreads();

  // ---- Layer 3: act frags hoisted
  {
    f16x8 axh[4], axl[4], ayh[4], ayl[4];
#pragma unroll
    for (int kc = 0; kc < 4; kc++) {
      int ko = kc * 32 + quad * 8;
      axh[kc] = *(const f16x8*)&AH[swz(ra, ko)];
      axl[kc] = *(const f16x8*)&AL[swz(ra, ko)];
      ayh[kc] = *(const f16x8*)&DH[swz(ra, ko)];
      ayl[kc] = *(const f16x8*)&DL[swz(ra, ko)];
    }
#pragma unroll
    for (int hf = 0; hf < 2; hf++) {
      if (hf == 1) {
        __syncthreads();
        cp_lds_async512(wd + 65536, Wreg, 32768, tid);  // W3-h1
        __syncthreads();
      }
      aP[hf] = zero; aS[hf] = zero; dP[hf] = zero; dS[hf] = zero;
#pragma unroll
      for (int kc = 0; kc < 4; kc++) {
        int ko = kc * 32 + quad * 8;
        f16x8 wh = *(const f16x8*)&Wreg[swz(hr, ko)];
        f16x8 wl = *(const f16x8*)&Wreg[8192 + swz(hr, ko)];
        aP[hf] = MFMA(wh, axh[kc], aP[hf]);
        aS[hf] = MFMA(wl, axh[kc], aS[hf]);
        aS[hf] = MFMA(wh, axl[kc], aS[hf]);
        dP[hf] = MFMA(wh, ayh[kc], dP[hf]);
        dS[hf] = MFMA(wl, ayh[kc], dS[hf]);
        dS[hf] = MFMA(wh, ayl[kc], dS[hf]);
      }
    }
  }
  __syncthreads();

  // ---- L3 epilogue -> swizzled f32 overlay
  {
    const float* b3d = b3 + d * Hh;
#pragma unroll
    for (int hf = 0; hf < 2; hf++) {
      int hb = hf * 64 + wq * 16 + quad * 4;
      float4 bv4 = *(const float4*)&b3d[hb];
      float4 pa, pd;
#pragma unroll
      for (int j = 0; j < 4; j++) {
        float p = aP[hf][j] + aS[hf][j] * INV2K + (&bv4.x)[j];
        float s = p > 0.f ? 1.f : SLP;
        (&pa.x)[j] = p * s;
        (&pd.x)[j] = s * (dP[hf][j] + dS[hf][j] * INV2K);
      }
      *(float4*)&A3F[swzF(ra, hb)] = pa;
      *(float4*)&D3F[swzF(ra, hb)] = pd;
    }
  }
  __syncthreads();

  // ---- Layer 4
  {
    int n = tid >> 4, g16 = tid & 15;
    const float* w4d = W4 + d * Hh;
    int c = g16 * 8;
    float4 va0 = *(const float4*)&A3F[swzF(n, c)];
    float4 va1 = *(const float4*)&A3F[swzF(n, c + 4)];
    float4 vd0 = *(const float4*)&D3F[swzF(n, c)];
    float4 vd1 = *(const float4*)&D3F[swzF(n, c + 4)];
    float4 w0 = *(const float4*)&w4d[c];
    float4 w1 = *(const float4*)&w4d[c + 4];
    float sr = va0.x * w0.x + va0.y * w0.y + va0.z * w0.z + va0.w * w0.w +
               va1.x * w1.x + va1.y * w1.y + va1.z * w1.z + va1.w * w1.w;
    float sd = vd0.x * w0.x + vd0.y * w0.y + vd0.z * w0.z + vd0.w * w0.w +
               vd1.x * w1.x + vd1.y * w1.y + vd1.z * w1.z + vd1.w * w1.w;
    sr += __shfl_xor(sr, 1); sr += __shfl_xor(sr, 2);
    sr += __shfl_xor(sr, 4); sr += __shfl_xor(sr, 8);
    sd += __shfl_xor(sd, 1); sd += __shfl_xor(sd, 2);
    sd += __shfl_xor(sd, 4); sd += __shfl_xor(sd, 8);
    if (g16 == 0) {
      int ng = n0 + n;
      out_res[ng * 64 + d] = sr + b4[d];
      atomicAdd(&out_log[ng], logf(fabsf(sd) + 1e-8f));
    }
  }
}

// ---------------- fallback (no-ws path, 256 threads) -------------------------
__device__ __forceinline__ void stage_wf(f16* WH, f16* WL,
                                         const float* __restrict__ g, int tid) {
  for (int i = tid; i < 2048; i += 256) {
    int h = i >> 5, k4 = (i & 31) << 2;
    float4 v = ((const float4*)g)[i];
    HL a = split(v.x), b = split(v.y), c = split(v.z), e = split(v.w);
    int o = swz(h, k4);
    *(f16x4*)&WH[o] = f16x4{a.h, b.h, c.h, e.h};
    *(f16x4*)&WL[o] = f16x4{a.l, b.l, c.l, e.l};
  }
}

__device__ __forceinline__ void mid_mfma_half(
    const f16* AH, const f16* AL, const f16* DH, const f16* DL,
    const f16* WH, const f16* WL, int nt, int wq, int l15, int quad,
    f32x4* aP, f32x4* aS, f32x4* dP, f32x4* dS) {
#pragma unroll
  for (int kc = 0; kc < 4; kc++) {
    int ko = kc * 32 + quad * 8;
    int ra = nt * 16 + l15;
    f16x8 xh = *(const f16x8*)&AH[swz(ra, ko)];
    f16x8 xl = *(const f16x8*)&AL[swz(ra, ko)];
    f16x8 yh = *(const f16x8*)&DH[swz(ra, ko)];
    f16x8 yl = *(const f16x8*)&DL[swz(ra, ko)];
#pragma unroll
    for (int c2 = 0; c2 < 2; c2++) {
      int hr = (2 * wq + c2) * 16 + l15;
      f16x8 wh = *(const f16x8*)&WH[swz(hr, ko)];
      f16x8 wl = *(const f16x8*)&WL[swz(hr, ko)];
      aP[c2] = MFMA(wh, xh, aP[c2]);
      aS[c2] = MFMA(wl, xh, aS[c2]);
      aS[c2] = MFMA(wh, xl, aS[c2]);
      dP[c2] = MFMA(wh, yh, dP[c2]);
      dS[c2] = MFMA(wl, yh, dS[c2]);
      dS[c2] = MFMA(wh, yl, dS[c2]);
    }
  }
}

__global__ __launch_bounds__(256, 2)
void np_prior_fb(const float* __restrict__ x,
                 const float* __restrict__ W1, const float* __restrict__ b1,
                 const float* __restrict__ W2, const float* __restrict__ b2,
                 const float* __restrict__ W3, const float* __restrict__ b3,
                 const float* __restrict__ W4, const float* __restrict__ b4,
                 float* __restrict__ out_res, float* __restrict__ out_log) {
  __shared__ float4 smem[4096];
  f16* AH = (f16*)smem;
  f16* AL = AH + NT * 128;
  f16* DH = AL + NT * 128;
  f16* DL = DH + NT * 128;
  f16* WHp = (f16*)((char*)smem + 32768);
  f16* WLp = WHp + 64 * 128;
  float* A3F = (float*)smem;
  float* D3F = (float*)((char*)smem + 16384);

  const int tid = threadIdx.x, d = blockIdx.y, n0 = blockIdx.x * NT;
  const int lane = tid & 63, wv = tid >> 6, l15 = lane & 15, quad = lane >> 4;
  const int nt = wv & 1, wq = wv >> 1;

  const float* W1d = W1 + d * Hh * 65;
  const float* b1d = b1 + d * Hh;
  const f32x4 zero = {0.f, 0.f, 0.f, 0.f};

  for (int i = tid; i < NT * 16; i += 256) {
    int n = i >> 4, k4 = (i & 15) << 2;
    int ng = n0 + n, bb = ng >> 8, tt = ng & 255;
    float4 v = *(const float4*)&x[(bb * 257 + tt) * 64 + k4];
    HL a = split(v.x), b = split(v.y), c = split(v.z), e = split(v.w);
    int o = swz(n, k4);
    *(f16x4*)&AH[o] = f16x4{a.h, b.h, c.h, e.h};
    *(f16x4*)&AL[o] = f16x4{a.l, b.l, c.l, e.l};
  }
  float xtv;
  {
    int ng = n0 + nt * 16 + l15, bb = ng >> 8, tt = ng & 255;
    xtv = x[(bb * 257 + tt + 1) * 64 + d];
  }
  for (int i = tid; i < 64 * 64; i += 256) {
    int h = i >> 6, k = i & 63;
    HL s = split(W1d[h * 65 + k]);
    int o = swz(h, k);
    WHp[o] = s.h; WLp[o] = s.l;
  }
  __syncthreads();

  f32x4 l1P[2][2], l1S[2][2];
  for (int hf = 0; hf < 2; hf++) {
    if (hf == 1) {
      __syncthreads();
      for (int i = tid; i < 64 * 64; i += 256) {
        int h = i >> 6, k = i & 63;
        HL s = split(W1d[(64 + h) * 65 + k]);
        int o = swz(h, k);
        WHp[o] = s.h; WLp[o] = s.l;
      }
      __syncthreads();
    }
    l1P[hf][0] = zero; l1P[hf][1] = zero;
    l1S[hf][0] = zero; l1S[hf][1] = zero;
#pragma unroll
    for (int kc = 0; kc < 2; kc++) {
      int ko = kc * 32 + quad * 8;
      f16x8 xh = *(const f16x8*)&AH[swz(nt * 16 + l15, ko)];
      f16x8 xl = *(const f16x8*)&AL[swz(nt * 16 + l15, ko)];
#pragma unroll
      for (int c2 = 0; c2 < 2; c2++) {
        int hr = (2 * wq + c2) * 16 + l15;
        f16x8 wh = *(const f16x8*)&WHp[swz(hr, ko)];
        f16x8 wl = *(const f16x8*)&WLp[swz(hr, ko)];
        l1P[hf][c2] = MFMA(wh, xh, l1P[hf][c2]);
        l1S[hf][c2] = MFMA(wl, xh, l1S[hf][c2]);
        l1S[hf][c2] = MFMA(wh, xl, l1S[hf][c2]);
      }
    }
  }
  __syncthreads();

  {
    int n = nt * 16 + l15;
#pragma unroll
    for (int hf = 0; hf < 2; hf++)
#pragma unroll
      for (int c2 = 0; c2 < 2; c2++) {
        int hb = hf * 64 + (2 * wq + c2) * 16 + quad * 4;
        f16x4 ah, al, dh, dl;
#pragma unroll
        for (int j = 0; j < 4; j++) {
          int h = hb + j;
          float w1j = W1d[h * 65 + 64];
          float p = l1P[hf][c2][j] + l1S[hf][c2][j] * INV2K + xtv * w1j + b1d[h];
          float s = p > 0.f ? 1.f : SLP;
          HL av = split(p * s), dv = split(s * w1j);
          ah[j] = av.h; al[j] = av.l; dh[j] = dv.h; dl[j] = dv.l;
        }
        int o = swz(n, hb);
        *(f16x4*)&AH[o] = ah; *(f16x4*)&AL[o] = al;
        *(f16x4*)&DH[o] = dh; *(f16x4*)&DL[o] = dl;
      }
  }
  stage_wf(WHp, WLp, W2 + d * Hh * Hh, tid);
  __syncthreads();

  f32x4 aP[2][2], aS[2][2], dP[2][2], dS[2][2];
  for (int hf = 0; hf < 2; hf++) {
    if (hf == 1) {
      __syncthreads();
      stage_wf(WHp, WLp, W2 + d * Hh * Hh + 64 * 128, tid);
      __syncthreads();
    }
    aP[hf][0] = zero; aP[hf][1] = zero; aS[hf][0] = zero; aS[hf][1] = zero;
    dP[hf][0] = zero; dP[hf][1] = zero; dS[hf][0] = zero; dS[hf][1] = zero;
    mid_mfma_half(AH, AL, DH, DL, WHp, WLp, nt, wq, l15, quad,
                  aP[hf], aS[hf], dP[hf], dS[hf]);
  }
  __syncthreads();

  {
    const float* b2d = b2 + d * Hh;
    int n = nt * 16 + l15;
#pragma unroll
    for (int hf = 0; hf < 2; hf++)
#pragma unroll
      for (int c2 = 0; c2 < 2; c2++) {
        int hb = hf * 64 + (2 * wq + c2) * 16 + quad * 4;
        f16x4 ah, al, dh, dl;
#pragma unroll
        for (int j = 0; j < 4; j++) {
          int h = hb + j;
          float p = aP[hf][c2][j] + aS[hf][c2][j] * INV2K + b2d[h];
          float s = p > 0.f ? 1.f : SLP;
          float dd = s * (dP[hf][c2][j] + dS[hf][c2][j] * INV2K);
          HL av = split(p * s), dv = split(dd);
          ah[j] = av.h; al[j] = av.l; dh[j] = dv.h; dl[j] = dv.l;
        }
        int o = swz(n, hb);
        *(f16x4*)&AH[o] = ah; *(f16x4*)&AL[o] = al;
        *(f16x4*)&DH[o] = dh; *(f16x4*)&DL[o] = dl;
      }
  }
  stage_wf(WHp, WLp, W3 + d * Hh * Hh, tid);
  __syncthreads();

  for (int hf = 0; hf < 2; hf++) {
    if (hf == 1) {
      __syncthreads();
      stage_wf(WHp, WLp, W3 + d * Hh * Hh + 64 * 128, tid);
      __syncthreads();
    }
    aP[hf][0] = zero; aP[hf][1] = zero; aS[hf][0] = zero; aS[hf][1] = zero;
    dP[hf][0] = zero; dP[hf][1] = zero; dS[hf][0] = zero; dS[hf][1] = zero;
    mid_mfma_half(AH, AL, DH, DL, WHp, WLp, nt, wq, l15, quad,
                  aP[hf], aS[hf], dP[hf], dS[hf]);
  }
  __syncthreads();

  {
    const float* b3d = b3 + d * Hh;
    int n = nt * 16 + l15;
#pragma unroll
    for (int hf = 0; hf < 2; hf++)
#pragma unroll
      for (int c2 = 0; c2 < 2; c2++) {
        int hb = hf * 64 + (2 * wq + c2) * 16 + quad * 4;
        float4 pa, pd;
#pragma unroll
        for (int j = 0; j < 4; j++) {
          int h = hb + j;
          float p = aP[hf][c2][j] + aS[hf][c2][j] * INV2K + b3d[h];
          float s = p > 0.f ? 1.f : SLP;
          (&pa.x)[j] = p * s;
          (&pd.x)[j] = s * (dP[hf][c2][j] + dS[hf][c2][j] * INV2K);
        }
        *(float4*)&A3F[swzF(n, hb)] = pa;
        *(float4*)&D3F[swzF(n, hb)] = pd;
      }
  }
  __syncthreads();

  {
    int n = tid >> 3, oct = tid & 7;
    const float* w4d = W4 + d * Hh;
    float sr = 0.f, sd = 0.f;
#pragma unroll
    for (int i = 0; i < 4; i++) {
      int c = oct * 16 + i * 4;
      float4 va = *(const float4*)&A3F[swzF(n, c)];
      float4 vd = *(const float4*)&D3F[swzF(n, c)];
      float4 w = *(const float4*)&w4d[c];
      sr += va.x * w.x + va.y * w.y + va.z * w.z + va.w * w.w;
      sd += vd.x * w.x + vd.y * w.y + vd.z * w.z + vd.w * w.w;
    }
    sr += __shfl_xor(sr, 1); sr += __shfl_xor(sr, 2); sr += __shfl_xor(sr, 4);
    sd += __shfl_xor(sd, 1); sd += __shfl_xor(sd, 2); sd += __shfl_xor(sd, 4);
    if (oct == 0) {
      int ng = n0 + n;
      out_res[ng * 64 + d] = sr + b4[d];
      atomicAdd(&out_log[ng], logf(fabsf(sd) + 1e-8f));
    }
  }
}

extern "C" void kernel_launch(void* const* d_in, const int* in_sizes, int n_in,
                              void* d_out, int out_size, void* d_ws, size_t ws_size,
                              hipStream_t stream) {
  (void)in_sizes; (void)n_in; (void)out_size;
  const float* x  = (const float*)d_in[0];
  const float* W1 = (const float*)d_in[1];
  const float* b1 = (const float*)d_in[2];
  const float* W2 = (const float*)d_in[3];
  const float* b2 = (const float*)d_in[4];
  const float* W3 = (const float*)d_in[5];
  const float* b3 = (const float*)d_in[6];
  const float* W4 = (const float*)d_in[7];
  const float* b4 = (const float*)d_in[8];

  float* out_res = (float*)d_out;
  float* out_log = out_res + Nn * Dd;

  if (ws_size >= WS_NEEDED) {
    f16* wsf = (f16*)d_ws;
    float* w1lg = (float*)((char*)d_ws + W1L_OFF);
    prep_kernel<<<2560, 256, 0, stream>>>(W1, W2, W3, wsf, w1lg, out_log);
    dim3 grid(Nn / NT, Dd);
    np_prior_fast<<<grid, 512, 0, stream>>>(x, wsf, w1lg, b1, b2, b3, W4, b4,
                                            out_res, out_log);
  } else {
    hipMemsetAsync(out_log, 0, Nn * sizeof(float), stream);
    dim3 grid(Nn / NT, Dd);
    np_prior_fb<<<grid, 256, 0, stream>>>(x, W1, b1, W2, b2, W3, b3, W4, b4,
                                          out_res, out_log);
  }
}